// Round 8
// baseline (419.839 us; speedup 1.0000x reference)
//
#include <hip/hip_runtime.h>
#include <hip/hip_bf16.h>
#include <math.h>

// Problem constants
#define B_  4
#define S_  2048
#define D_  1024
#define H_  16
#define HD_ 64

typedef __bf16 bf16;
typedef __bf16 bf16x4 __attribute__((ext_vector_type(4)));
typedef __bf16 bf16x8 __attribute__((ext_vector_type(8)));
typedef float  floatx4 __attribute__((ext_vector_type(4)));

// log2(e)/8: folds the 1/sqrt(64) attention scale AND the exp->exp2 change
// of base into the Q projection epilogue.
#define QSCALE 0.18033688011112042f

// Async global->LDS DMA, 16B/lane. LDS dest = wave-uniform base + lane*16.
__device__ __forceinline__ void async_load16(const bf16* g, bf16* l) {
  __builtin_amdgcn_global_load_lds(
      (const __attribute__((address_space(1))) void*)g,
      (__attribute__((address_space(3))) void*)l, 16, 0, 0);
}

// ---------------------------------------------------------------------------
// Merged input-cast + weight-transpose (one launch, block-ranged):
// blocks [0,16384): fp32->bf16 cast of X_Q / X_KV (8192 each)
// blocks [16384,20480): fp32 [K][N] -> bf16 [N][K] transpose of 3 weights
// ---------------------------------------------------------------------------
__global__ __launch_bounds__(256) void prep_all(
    const float* __restrict__ xa, bf16* __restrict__ oa,
    const float* __restrict__ xb, bf16* __restrict__ ob,
    const float* __restrict__ qw, bf16* __restrict__ qwT,
    const float* __restrict__ kvw, bf16* __restrict__ kvwT,
    const float* __restrict__ ow, bf16* __restrict__ owT) {
  __shared__ float tile[32][33];
  int bid = blockIdx.x;
  if (bid < 16384) {
    const float* in; bf16* out; int i;
    if (bid < 8192) { in = xa; out = oa; i = (bid * 256 + threadIdx.x) * 4; }
    else            { in = xb; out = ob; i = ((bid - 8192) * 256 + threadIdx.x) * 4; }
    float4 v = *reinterpret_cast<const float4*>(in + i);
    bf16x4 o;
    o[0] = (bf16)v.x; o[1] = (bf16)v.y; o[2] = (bf16)v.z; o[3] = (bf16)v.w;
    *reinterpret_cast<bf16x4*>(out + i) = o;
    return;
  }
  bid -= 16384;
  const float* in; bf16* out; int N, lb;
  if (bid < 1024)      { in = qw;  out = qwT;  N = 1024; lb = bid; }
  else if (bid < 3072) { in = kvw; out = kvwT; N = 2048; lb = bid - 1024; }
  else                 { in = ow;  out = owT;  N = 1024; lb = bid - 3072; }
  int nx = N >> 5;
  int n0 = (lb % nx) * 32, k0 = (lb / nx) * 32;
  int tx = threadIdx.x & 31, ty = threadIdx.x >> 5;  // 32 x 8
  #pragma unroll
  for (int i = ty; i < 32; i += 8)
    tile[i][tx] = in[(size_t)(k0 + i) * N + n0 + tx];
  __syncthreads();
  #pragma unroll
  for (int i = ty; i < 32; i += 8)
    out[(size_t)(n0 + i) * 1024 + k0 + tx] = (bf16)tile[tx][i];
}

// ---------------------------------------------------------------------------
// bf16 GEMM body, m97 structure: C[M,N] = A[M,K] @ Bt[N,K]^T + bias[N]
// 128x128 tile, BK=64, global_load_lds(16B) staging, XOR-swizzled LDS.
// MODE 0: fp32 out row-major [M,N]
// MODE 1: bf16 out in Q layout [B,H,S,HD], scaled by QSCALE (N==1024)
// MODE 2: bf16 out; K half -> [B,H,S,HD]; V half -> TRANSPOSED [B,H,HD,S]
// SWAP: operands reversed in the MFMA (D^T): the accumulator reg-dim then
// runs along N, so MODE0 packs float4 and MODE1/2-K pack bf16x4 along d
// (4x fewer store instructions vs scalar 2B/4B stores).
// Verified mapping (attn QK^T convention, D[row=A-free][col=B-free]):
//   normal: acc[i][j] row = m0+wm+16i+4lq+r, col = n0+wn+16j+lr
//   SWAP:   acc[i][j] col = n0+wn+16i+4lq+r, row = m0+wm+16j+lr
// V-half (bx>=8 of the KV GEMM) keeps normal orientation: its s-contiguous
// bf16x4 packing is already optimal in the [B,H,HD,S] layout.
// ---------------------------------------------------------------------------
template <int MODE, bool SWAP>
__device__ __forceinline__ void gemm_body(
    const bf16* __restrict__ A, const bf16* __restrict__ Bt,
    const float* __restrict__ bias, void* __restrict__ out,
    int M, int N, int K, int bx, int by,
    bf16 (*As)[64], bf16 (*Bs)[64]) {
  const int tid  = threadIdx.x;
  const int m0   = by * 128;
  const int n0   = bx * 128;
  const int w    = tid >> 6;
  const int lane = tid & 63;
  const int lr   = lane & 15;
  const int lq   = lane >> 4;
  const int wm   = (w >> 1) * 64;
  const int wn   = (w & 1) * 64;

  const int srow = lane >> 3;
  const int sg   = (lane & 7) ^ srow;
  const bf16* aptr = A  + (size_t)(m0 + 32 * w + srow) * K + 8 * sg;
  const bf16* bptr = Bt + (size_t)(n0 + 32 * w + srow) * K + 8 * sg;

  floatx4 acc[4][4];
  #pragma unroll
  for (int i = 0; i < 4; i++)
    #pragma unroll
    for (int j = 0; j < 4; j++)
      acc[i][j] = floatx4{0.f, 0.f, 0.f, 0.f};

  for (int k0 = 0; k0 < K; k0 += 64) {
    __syncthreads();
    #pragma unroll
    for (int p = 0; p < 4; p++) {
      async_load16(aptr + (size_t)8 * p * K + k0, &As[32 * w + 8 * p][0]);
      async_load16(bptr + (size_t)8 * p * K + k0, &Bs[32 * w + 8 * p][0]);
    }
    __syncthreads();  // drains vmcnt(0): staged data visible
    #pragma unroll
    for (int kc = 0; kc < 2; kc++) {
      const int sw = 8 * ((kc * 4 + lq) ^ (lr & 7));
      bf16x8 af[4], bfv[4];
      #pragma unroll
      for (int t = 0; t < 4; t++)
        af[t] = *reinterpret_cast<const bf16x8*>(&As[wm + 16 * t + lr][sw]);
      #pragma unroll
      for (int t = 0; t < 4; t++)
        bfv[t] = *reinterpret_cast<const bf16x8*>(&Bs[wn + 16 * t + lr][sw]);
      #pragma unroll
      for (int i = 0; i < 4; i++)
        #pragma unroll
        for (int j = 0; j < 4; j++) {
          if (SWAP)
            acc[i][j] = __builtin_amdgcn_mfma_f32_16x16x32_bf16(bfv[i], af[j], acc[i][j], 0, 0, 0);
          else
            acc[i][j] = __builtin_amdgcn_mfma_f32_16x16x32_bf16(af[i], bfv[j], acc[i][j], 0, 0, 0);
        }
    }
  }

  if (SWAP) {
    // acc[i][j]: col base = n0+wn+16i+4lq (reg r along n), row = m0+wm+16j+lr
    #pragma unroll
    for (int i = 0; i < 4; i++) {
      const int colb = n0 + wn + 16 * i + 4 * lq;
      const floatx4 bv4 = *reinterpret_cast<const floatx4*>(&bias[colb]);
      #pragma unroll
      for (int j = 0; j < 4; j++) {
        const int row = m0 + wm + 16 * j + lr;
        if (MODE == 0) {
          floatx4 v = acc[i][j] + bv4;
          *reinterpret_cast<floatx4*>(&((float*)out)[(size_t)row * N + colb]) = v;
        } else {
          const int b = row >> 11, s = row & 2047;
          const int h = colb >> 6, d0 = colb & 63;
          bf16x4 pk;
          #pragma unroll
          for (int r = 0; r < 4; r++) {
            float v = acc[i][j][r] + bv4[r];
            pk[r] = (bf16)(MODE == 1 ? v * QSCALE : v);
          }
          *reinterpret_cast<bf16x4*>(
              &((bf16*)out)[(((size_t)b * H_ + h) * S_ + s) * HD_ + d0]) = pk;
        }
      }
    }
    return;
  }

  // normal epilogue (C/D: col=lane&15, row=(lane>>4)*4+reg)
  #pragma unroll
  for (int i = 0; i < 4; i++) {
    int row_base = m0 + wm + 16 * i + lq * 4;
    #pragma unroll
    for (int j = 0; j < 4; j++) {
      int col = n0 + wn + 16 * j + lr;
      float bv = bias[col];
      if (MODE == 2 && col >= 1024) {
        int b = row_base >> 11, s0 = row_base & 2047;
        int c = col - 1024, h = c >> 6, d = c & 63;
        bf16* Vt = (bf16*)out + (size_t)B_ * H_ * S_ * HD_;
        bf16x4 pk;
        #pragma unroll
        for (int r = 0; r < 4; r++) pk[r] = (bf16)(acc[i][j][r] + bv);
        *reinterpret_cast<bf16x4*>(
            &Vt[(((size_t)b * H_ + h) * HD_ + d) * S_ + s0]) = pk;
        continue;
      }
      #pragma unroll
      for (int r = 0; r < 4; r++) {
        int row = row_base + r;
        float v = acc[i][j][r] + bv;
        if (MODE == 0) {
          ((float*)out)[(size_t)row * N + col] = v;
        } else {
          int b = row >> 11, s = row & 2047;
          int h = col >> 6, d = col & 63;
          ((bf16*)out)[(((size_t)b * H_ + h) * S_ + s) * HD_ + d] =
              (bf16)(MODE == 1 ? v * QSCALE : v);
        }
      }
    }
  }
}

// out-projection GEMM (fp32 out), plain grid, swapped for float4 stores
__global__ __launch_bounds__(256) void gemm_out(
    const bf16* __restrict__ A, const bf16* __restrict__ Bt,
    const float* __restrict__ bias, void* __restrict__ out,
    int M, int N, int K) {
  __shared__ bf16 As[128][64];
  __shared__ bf16 Bs[128][64];
  gemm_body<0, true>(A, Bt, bias, out, M, N, K, blockIdx.x, blockIdx.y, As, Bs);
}

// Merged Q-projection + KV-projection in ONE launch (block-range dispatch).
// Q blocks and the K-half of KV use SWAP (bf16x4 stores along d); the V-half
// (bx>=8) keeps normal orientation (bf16x4 along s in the [B,H,HD,S] layout).
__global__ __launch_bounds__(256) void gemm_qkv(
    const bf16* __restrict__ Xq, const bf16* __restrict__ qwT,
    const float* __restrict__ q_b, bf16* __restrict__ Qb,
    const bf16* __restrict__ Xkv, const bf16* __restrict__ kvwT,
    const float* __restrict__ kv_b, bf16* __restrict__ KVb) {
  __shared__ bf16 As[128][64];
  __shared__ bf16 Bs[128][64];
  int bid = blockIdx.x;
  if (bid < 512) {
    gemm_body<1, true>(Xq, qwT, q_b, Qb, 8192, 1024, 1024, bid & 7, bid >> 3, As, Bs);
  } else {
    int b2 = bid - 512;
    int bx = b2 & 15, by = b2 >> 4;
    if (bx < 8)
      gemm_body<2, true>(Xkv, kvwT, kv_b, KVb, 8192, 2048, 1024, bx, by, As, Bs);
    else
      gemm_body<2, false>(Xkv, kvwT, kv_b, KVb, 8192, 2048, 1024, bx, by, As, Bs);
  }
}

// ---------------------------------------------------------------------------
// Attention v8: decoupled waves (v7) + K REGISTER DOUBLE-BUFFER.
// v7's regression isolated the fault: K fragments were loaded immediately
// before their consuming MFMA -> ~200cyc L2 latency x 8 loads serialized per
// iter (iter 6.7k -> 10.2k cyc). v8 ping-pongs K fragments (kA/kB, 8 x
// bf16x8 each) with next-iter loads issued at the TOP of the current iter —
// a full iteration (~2k cyc) of cover. V keeps the proven phase-early
// issue (A->B, C->D distance ~300-500 cyc > 200). Q in regs; P in per-wave
// conflict-free 4KB LDS (XOR lr>>1, zero conflicts measured); NO
// __syncthreads in the main loop; K/V straight from L2 (bh-major grid
// keeps each XCD's K/V at 4MB = L2 size; FETCH 24.6MB confirms).
// Schedule per 64-key tile: A:QK^T(0-31) | B:PV kc0 | C:QK^T(32-63) | D:PV1.
// S^T = K@Q^T; p = exp2(s) (scale folded into Q; no running max needed).
// O^T = V^T@P^T with V^T precomputed by the KV GEMM. LDS: P only, 16KB.
// ---------------------------------------------------------------------------
__global__ __launch_bounds__(256, 2) void attn_kernel(
    const bf16* __restrict__ Q, const bf16* __restrict__ Kb,
    const bf16* __restrict__ Vt, bf16* __restrict__ out) {
  __shared__ bf16 smem[8192];           // P: 4 waves x 2048 (4KB each)

  const int tid  = threadIdx.x;
  const int w    = tid >> 6;            // 0..3
  const int lane = tid & 63;
  const int lr   = lane & 15;
  const int lq   = lane >> 4;
  const int bh   = blockIdx.x;          // x-major -> head's q-tiles same XCD
  const int q0   = blockIdx.y * 256;
  const size_t base = (size_t)bh * S_ * HD_;

  bf16* pw = smem + w * 2048;           // wave's P: [64 q][32 keys], swizzled

  // direct-global fragment bases
  // K: lane reads K[key = it*64 + 16t + lr][d = 8lq..8lq+7 (+32 for hi)]
  const bf16* kit = Kb + base + (size_t)lr * HD_ + 8 * lq;
  // V^T: lane reads Vt[d = 16t2 + lr][key = it*64 + 32kc + 8lq..]
  const bf16* vit = Vt + base + (size_t)lr * S_ + 8 * lq;

  // Q fragments from global (B-layout: n=lr -> q row, k=32kc+8lq+j)
  bf16x8 bq[4][2];
  #pragma unroll
  for (int g = 0; g < 4; g++) {
    const bf16* qrow = Q + base + (size_t)(q0 + 64 * w + 16 * g + lr) * HD_;
    bq[g][0] = *reinterpret_cast<const bf16x8*>(qrow + lq * 8);
    bq[g][1] = *reinterpret_cast<const bf16x8*>(qrow + 32 + lq * 8);
  }

  const int plx = lr >> 1;              // 3-bit P-swizzle, orthogonal to lr&1

  float l_i[4] = {0.f, 0.f, 0.f, 0.f};
  floatx4 o_acc[4][4];
  #pragma unroll
  for (int g = 0; g < 4; g++)
    #pragma unroll
    for (int t = 0; t < 4; t++) o_acc[g][t] = floatx4{0.f, 0.f, 0.f, 0.f};

  const int NIT = S_ / 64;

  // prologue: K fragments for iter 0; kit then points at iter 1
  bf16x8 kA[8], kB[8];
  #pragma unroll
  for (int t = 0; t < 4; t++) {
    kA[2 * t]     = *reinterpret_cast<const bf16x8*>(kit + 16 * t * HD_);
    kA[2 * t + 1] = *reinterpret_cast<const bf16x8*>(kit + 16 * t * HD_ + 32);
  }
  kit += 64 * HD_;

  // one 64-key iteration consuming `cur`, prefetching K into `nxt`
  auto body = [&](bf16x8 (&cur)[8], bf16x8 (&nxt)[8], int it) {
    // K prefetch for it+1 at max distance
    if (it + 1 < NIT) {
      #pragma unroll
      for (int t = 0; t < 4; t++) {
        nxt[2 * t]     = *reinterpret_cast<const bf16x8*>(kit + 16 * t * HD_);
        nxt[2 * t + 1] = *reinterpret_cast<const bf16x8*>(kit + 16 * t * HD_ + 32);
      }
      kit += 64 * HD_;
    }

    // QK^T + exp + P-write for 16-key block t; P slot group = 4*(t&1)+lq
    auto qkt = [&](int t) {
      floatx4 sc[4];
      #pragma unroll
      for (int g = 0; g < 4; g++) {
        sc[g] = __builtin_amdgcn_mfma_f32_16x16x32_bf16(cur[2 * t], bq[g][0],
                    floatx4{0.f, 0.f, 0.f, 0.f}, 0, 0, 0);
        sc[g] = __builtin_amdgcn_mfma_f32_16x16x32_bf16(cur[2 * t + 1], bq[g][1], sc[g], 0, 0, 0);
      }
      const int pcol = 4 * ((4 * (t & 1) + lq) ^ plx);
      #pragma unroll
      for (int g = 0; g < 4; g++) {
        bf16x4 pk;
        float lsum = 0.f;
        #pragma unroll
        for (int r = 0; r < 4; r++) {
          float p = __builtin_amdgcn_exp2f(sc[g][r]);
          lsum += p;
          pk[r] = (bf16)p;
        }
        l_i[g] += lsum;
        *reinterpret_cast<bf16x4*>(&pw[(16 * g + lr) * 32 + pcol]) = pk;
      }
    };

    // PV for one 32-key half; V fragments were loaded a phase early
    auto pv = [&](const bf16x8* av) {
      bf16x8 bp[4];
      #pragma unroll
      for (int g = 0; g < 4; g++) {
        union { bf16x4 h[2]; bf16x8 v; } f;
        f.h[0] = *reinterpret_cast<const bf16x4*>(
            &pw[(16 * g + lr) * 32 + 4 * ((2 * lq + 0) ^ plx)]);
        f.h[1] = *reinterpret_cast<const bf16x4*>(
            &pw[(16 * g + lr) * 32 + 4 * ((2 * lq + 1) ^ plx)]);
        bp[g] = f.v;
      }
      __builtin_amdgcn_s_setprio(1);
      #pragma unroll
      for (int t2 = 0; t2 < 4; t2++)
        #pragma unroll
        for (int g = 0; g < 4; g++)
          o_acc[g][t2] = __builtin_amdgcn_mfma_f32_16x16x32_bf16(av[t2], bp[g], o_acc[g][t2], 0, 0, 0);
      __builtin_amdgcn_s_setprio(0);
    };

    // A: V(kc=0) loads issued early; QK^T keys 0-31 -> P
    bf16x8 av0[4];
    #pragma unroll
    for (int t2 = 0; t2 < 4; t2++)
      av0[t2] = *reinterpret_cast<const bf16x8*>(vit + (size_t)16 * t2 * S_);
    qkt(0);
    qkt(1);
    __builtin_amdgcn_wave_barrier();  // pin ds_write -> ds_read (same wave)
    // B: PV kc=0
    pv(av0);
    __builtin_amdgcn_wave_barrier();  // pin B reads -> C overwrites
    // C: V(kc=1) loads issued early; QK^T keys 32-63 -> P (overwrite)
    bf16x8 av1[4];
    #pragma unroll
    for (int t2 = 0; t2 < 4; t2++)
      av1[t2] = *reinterpret_cast<const bf16x8*>(vit + (size_t)16 * t2 * S_ + 32);
    qkt(2);
    qkt(3);
    __builtin_amdgcn_wave_barrier();  // pin ds_write -> ds_read
    // D: PV kc=1
    pv(av1);

    vit += 64;
  };

  for (int it = 0; it < NIT; it += 2) {
    body(kA, kB, it);
    body(kB, kA, it + 1);
  }

  // finish denom: sum across the 4 lq groups sharing q=lr
  #pragma unroll
  for (int g = 0; g < 4; g++) {
    l_i[g] += __shfl_xor(l_i[g], 16, 64);
    l_i[g] += __shfl_xor(l_i[g], 32, 64);
  }

  // epilogue: out[b, s=q0+64w+16g+lr, h*64 + 16t + 4lq + r]
  const int b = bh >> 4, h = bh & 15;
  #pragma unroll
  for (int g = 0; g < 4; g++) {
    const float inv = 1.0f / l_i[g];
    const int qrow = q0 + 64 * w + 16 * g + lr;
    bf16* orow = out + ((size_t)b * S_ + qrow) * D_ + h * HD_;
    #pragma unroll
    for (int t = 0; t < 4; t++) {
      bf16x4 pk;
      #pragma unroll
      for (int r = 0; r < 4; r++) pk[r] = (bf16)(o_acc[g][t][r] * inv);
      *reinterpret_cast<bf16x4*>(&orow[16 * t + lq * 4]) = pk;
    }
  }
}

// ---------------------------------------------------------------------------
extern "C" void kernel_launch(void* const* d_in, const int* in_sizes, int n_in,
                              void* d_out, int out_size, void* d_ws, size_t ws_size,
                              hipStream_t stream) {
  const float* X_Q   = (const float*)d_in[0];
  const float* X_KV  = (const float*)d_in[1];
  const float* q_w   = (const float*)d_in[2];
  const float* q_b   = (const float*)d_in[3];
  const float* kv_w  = (const float*)d_in[4];
  const float* kv_b  = (const float*)d_in[5];
  const float* out_w = (const float*)d_in[6];
  const float* out_b = (const float*)d_in[7];
  float* out = (float*)d_out;

  char* ws = (char*)d_ws;
  const size_t MB = 1024 * 1024;
  bf16* Xq   = (bf16*)(ws + 0);         // 16MB (reused as attn output later)
  bf16* Xkv  = (bf16*)(ws + 16 * MB);   // 16MB
  bf16* Qb   = (bf16*)(ws + 32 * MB);   // 16MB  [B,H,S,HD] (pre-scaled)
  bf16* Kb   = (bf16*)(ws + 48 * MB);   // 16MB  [B,H,S,HD]; Vt follows at +16MB
  bf16* qwT  = (bf16*)(ws + 80 * MB);   // 2MB   [N=1024][K=1024]
  bf16* kvwT = (bf16*)(ws + 82 * MB);   // 4MB   [N=2048][K=1024]
  bf16* owT  = (bf16*)(ws + 86 * MB);   // 2MB
  bf16* Vt   = Kb + (size_t)B_ * H_ * S_ * HD_;  // [B,H,HD,S]
  bf16* attn = Xq;                       // alias: X_Q bf16 dead after GEMM1

  // merged cast + weight transpose (one launch)
  prep_all<<<20480, 256, 0, stream>>>(X_Q, Xq, X_KV, Xkv,
                                      q_w, qwT, kv_w, kvwT, out_w, owT);
  // merged: Q = (Xq @ q_w + q_b)*QSCALE  and  KV = Xkv @ kv_w + kv_b
  gemm_qkv<<<1536, 256, 0, stream>>>(Xq, qwT, q_b, Qb, Xkv, kvwT, kv_b, Kb);
  // attention (256 q-rows per block, decoupled waves + K reg dbuf)
  attn_kernel<<<dim3(64, 8), 256, 0, stream>>>(Qb, Kb, Vt, attn);
  // out = attn @ out_w + out_b  (fp32)
  gemm_out<<<dim3(8, 64), 256, 0, stream>>>(attn, owT, out_b, out, 8192, 1024, 1024);
}

// Round 9
// 318.592 us; speedup vs baseline: 1.3178x; 1.3178x over previous
//
#include <hip/hip_runtime.h>
#include <hip/hip_bf16.h>
#include <math.h>

// Problem constants
#define B_  4
#define S_  2048
#define D_  1024
#define H_  16
#define HD_ 64

typedef __bf16 bf16;
typedef __bf16 bf16x4 __attribute__((ext_vector_type(4)));
typedef __bf16 bf16x8 __attribute__((ext_vector_type(8)));
typedef float  floatx4 __attribute__((ext_vector_type(4)));

// log2(e)/8: folds the 1/sqrt(64) attention scale AND the exp->exp2 change
// of base into the Q projection epilogue.
#define QSCALE 0.18033688011112042f

// Async global->LDS DMA, 16B/lane. LDS dest = wave-uniform base + lane*16.
__device__ __forceinline__ void async_load16(const bf16* g, bf16* l) {
  __builtin_amdgcn_global_load_lds(
      (const __attribute__((address_space(1))) void*)g,
      (__attribute__((address_space(3))) void*)l, 16, 0, 0);
}

// ---------------------------------------------------------------------------
// Merged input-cast + weight-transpose (one launch, block-ranged):
// blocks [0,16384): fp32->bf16 cast of X_Q / X_KV (8192 each)
// blocks [16384,20480): fp32 [K][N] -> bf16 [N][K] transpose of 3 weights
// ---------------------------------------------------------------------------
__global__ __launch_bounds__(256) void prep_all(
    const float* __restrict__ xa, bf16* __restrict__ oa,
    const float* __restrict__ xb, bf16* __restrict__ ob,
    const float* __restrict__ qw, bf16* __restrict__ qwT,
    const float* __restrict__ kvw, bf16* __restrict__ kvwT,
    const float* __restrict__ ow, bf16* __restrict__ owT) {
  __shared__ float tile[32][33];
  int bid = blockIdx.x;
  if (bid < 16384) {
    const float* in; bf16* out; int i;
    if (bid < 8192) { in = xa; out = oa; i = (bid * 256 + threadIdx.x) * 4; }
    else            { in = xb; out = ob; i = ((bid - 8192) * 256 + threadIdx.x) * 4; }
    float4 v = *reinterpret_cast<const float4*>(in + i);
    bf16x4 o;
    o[0] = (bf16)v.x; o[1] = (bf16)v.y; o[2] = (bf16)v.z; o[3] = (bf16)v.w;
    *reinterpret_cast<bf16x4*>(out + i) = o;
    return;
  }
  bid -= 16384;
  const float* in; bf16* out; int N, lb;
  if (bid < 1024)      { in = qw;  out = qwT;  N = 1024; lb = bid; }
  else if (bid < 3072) { in = kvw; out = kvwT; N = 2048; lb = bid - 1024; }
  else                 { in = ow;  out = owT;  N = 1024; lb = bid - 3072; }
  int nx = N >> 5;
  int n0 = (lb % nx) * 32, k0 = (lb / nx) * 32;
  int tx = threadIdx.x & 31, ty = threadIdx.x >> 5;  // 32 x 8
  #pragma unroll
  for (int i = ty; i < 32; i += 8)
    tile[i][tx] = in[(size_t)(k0 + i) * N + n0 + tx];
  __syncthreads();
  #pragma unroll
  for (int i = ty; i < 32; i += 8)
    out[(size_t)(n0 + i) * 1024 + k0 + tx] = (bf16)tile[tx][i];
}

// ---------------------------------------------------------------------------
// bf16 GEMM body, m97 structure: C[M,N] = A[M,K] @ Bt[N,K]^T + bias[N]
// 128x128 tile, BK=64, global_load_lds(16B) staging, XOR-swizzled LDS.
// MODE 0: fp32 out row-major [M,N]
// MODE 1: bf16 out in Q layout [B,H,S,HD], scaled by QSCALE (N==1024)
// MODE 2: bf16 out; K half -> [B,H,S,HD]; V half -> TRANSPOSED [B,H,HD,S]
// (SWAP epilogue from round 8 reverted: its strided 16B stores cost ~12us
//  on the non-attn side vs the normal orientation.)
// ---------------------------------------------------------------------------
template <int MODE>
__device__ __forceinline__ void gemm_body(
    const bf16* __restrict__ A, const bf16* __restrict__ Bt,
    const float* __restrict__ bias, void* __restrict__ out,
    int M, int N, int K, int bx, int by,
    bf16 (*As)[64], bf16 (*Bs)[64]) {
  const int tid  = threadIdx.x;
  const int m0   = by * 128;
  const int n0   = bx * 128;
  const int w    = tid >> 6;
  const int lane = tid & 63;
  const int lr   = lane & 15;
  const int lq   = lane >> 4;
  const int wm   = (w >> 1) * 64;
  const int wn   = (w & 1) * 64;

  const int srow = lane >> 3;
  const int sg   = (lane & 7) ^ srow;
  const bf16* aptr = A  + (size_t)(m0 + 32 * w + srow) * K + 8 * sg;
  const bf16* bptr = Bt + (size_t)(n0 + 32 * w + srow) * K + 8 * sg;

  floatx4 acc[4][4];
  #pragma unroll
  for (int i = 0; i < 4; i++)
    #pragma unroll
    for (int j = 0; j < 4; j++)
      acc[i][j] = floatx4{0.f, 0.f, 0.f, 0.f};

  for (int k0 = 0; k0 < K; k0 += 64) {
    __syncthreads();
    #pragma unroll
    for (int p = 0; p < 4; p++) {
      async_load16(aptr + (size_t)8 * p * K + k0, &As[32 * w + 8 * p][0]);
      async_load16(bptr + (size_t)8 * p * K + k0, &Bs[32 * w + 8 * p][0]);
    }
    __syncthreads();  // drains vmcnt(0): staged data visible
    #pragma unroll
    for (int kc = 0; kc < 2; kc++) {
      const int sw = 8 * ((kc * 4 + lq) ^ (lr & 7));
      bf16x8 af[4], bfv[4];
      #pragma unroll
      for (int t = 0; t < 4; t++)
        af[t] = *reinterpret_cast<const bf16x8*>(&As[wm + 16 * t + lr][sw]);
      #pragma unroll
      for (int t = 0; t < 4; t++)
        bfv[t] = *reinterpret_cast<const bf16x8*>(&Bs[wn + 16 * t + lr][sw]);
      #pragma unroll
      for (int i = 0; i < 4; i++)
        #pragma unroll
        for (int j = 0; j < 4; j++)
          acc[i][j] = __builtin_amdgcn_mfma_f32_16x16x32_bf16(af[i], bfv[j], acc[i][j], 0, 0, 0);
    }
  }

  // epilogue (C/D: col=lane&15, row=(lane>>4)*4+reg)
  #pragma unroll
  for (int i = 0; i < 4; i++) {
    int row_base = m0 + wm + 16 * i + lq * 4;
    #pragma unroll
    for (int j = 0; j < 4; j++) {
      int col = n0 + wn + 16 * j + lr;
      float bv = bias[col];
      if (MODE == 2 && col >= 1024) {
        int b = row_base >> 11, s0 = row_base & 2047;
        int c = col - 1024, h = c >> 6, d = c & 63;
        bf16* Vt = (bf16*)out + (size_t)B_ * H_ * S_ * HD_;
        bf16x4 pk;
        #pragma unroll
        for (int r = 0; r < 4; r++) pk[r] = (bf16)(acc[i][j][r] + bv);
        *reinterpret_cast<bf16x4*>(
            &Vt[(((size_t)b * H_ + h) * HD_ + d) * S_ + s0]) = pk;
        continue;
      }
      #pragma unroll
      for (int r = 0; r < 4; r++) {
        int row = row_base + r;
        float v = acc[i][j][r] + bv;
        if (MODE == 0) {
          ((float*)out)[(size_t)row * N + col] = v;
        } else if (MODE == 1) {
          int b = row >> 11, s = row & 2047;
          int h = col >> 6, d = col & 63;
          ((bf16*)out)[(((size_t)b * H_ + h) * S_ + s) * HD_ + d] =
              (bf16)(v * QSCALE);
        } else {
          int b = row >> 11, s = row & 2047;
          int h = col >> 6, d = col & 63;
          ((bf16*)out)[(((size_t)b * H_ + h) * S_ + s) * HD_ + d] = (bf16)v;
        }
      }
    }
  }
}

// out-projection GEMM (fp32 out), plain grid
__global__ __launch_bounds__(256) void gemm_out(
    const bf16* __restrict__ A, const bf16* __restrict__ Bt,
    const float* __restrict__ bias, void* __restrict__ out,
    int M, int N, int K) {
  __shared__ bf16 As[128][64];
  __shared__ bf16 Bs[128][64];
  gemm_body<0>(A, Bt, bias, out, M, N, K, blockIdx.x, blockIdx.y, As, Bs);
}

// Merged Q-projection + KV-projection in ONE launch (block-range dispatch).
__global__ __launch_bounds__(256) void gemm_qkv(
    const bf16* __restrict__ Xq, const bf16* __restrict__ qwT,
    const float* __restrict__ q_b, bf16* __restrict__ Qb,
    const bf16* __restrict__ Xkv, const bf16* __restrict__ kvwT,
    const float* __restrict__ kv_b, bf16* __restrict__ KVb) {
  __shared__ bf16 As[128][64];
  __shared__ bf16 Bs[128][64];
  int bid = blockIdx.x;
  if (bid < 512) {
    gemm_body<1>(Xq, qwT, q_b, Qb, 8192, 1024, 1024, bid & 7, bid >> 3, As, Bs);
  } else {
    int b2 = bid - 512;
    gemm_body<2>(Xkv, kvwT, kv_b, KVb, 8192, 2048, 1024, b2 & 15, b2 >> 4, As, Bs);
  }
}

// ---------------------------------------------------------------------------
// Attention v9: KEY-SPLIT occupancy doubling. 512 threads = 8 waves; waves
// 0-3 (grp 0) process keys 0-1023, waves 4-7 (grp 1) keys 1024-2047, for the
// SAME 256 q-rows (wave wl=w&3 owns 64 q). Per-wave inner loop is byte-for-
// byte the proven v6 structure (88.5-89.8us at 2 waves/SIMD): K LDS-staged
// double-buffered per group, P in per-wave conflict-free 4KB LDS, 4-phase
// A:QK^T(0-31)|B:PV0|C:QK^T(32-63)|D:PV1. Each wave runs 16 (not 32) iters.
// V is NOT LDS-staged (v7 proved direct-L2 V with phase-early issue is fine;
// only unprefetched K convoyed) — that frees the LDS to fit: K-dbuf 8KB x2
// groups + P 8x4KB = 64KB -> 2 blocks/CU -> 4 waves/SIMD (was 2).
// Partial (o_acc, l_i) combine linearly (no-max softmax is a plain sum):
// grp1 -> LDS -> grp0 two-phase reduction at the end (~1-2us, conflict-free
// slot-major layout), grp0 writes output.
// Register budget: v6 measured 84, v7 96; this is the same structure -> ~100
// < 128 cap at (512,2) under either launch_bounds semantics. WRITE_SIZE is
// the spill tripwire (must stay ~16MB).
// bh-major grid keeps each XCD's K/V at 4MB = L2 size (FETCH 24.6MB).
// S^T = K@Q^T; p = exp2(s) (scale folded into Q; no running max needed).
// O^T = V^T@P^T with V^T precomputed by the KV GEMM.
// ---------------------------------------------------------------------------
__global__ __launch_bounds__(512, 2) void attn_kernel(
    const bf16* __restrict__ Q, const bf16* __restrict__ Kb,
    const bf16* __restrict__ Vt, bf16* __restrict__ out) {
  __shared__ bf16 smem[32768];  // [g0 K-dbuf 16KB][g1 K-dbuf 16KB][P 8x4KB]

  const int tid  = threadIdx.x;
  const int w    = tid >> 6;            // 0..7
  const int wl   = w & 3;               // wave within key-group
  const int grp  = w >> 2;              // key-group
  const int lane = tid & 63;
  const int lr   = lane & 15;
  const int lq   = lane >> 4;
  const int bh   = blockIdx.x;          // x-major -> head's q-tiles same XCD
  const int q0   = blockIdx.y * 256;
  const size_t base = (size_t)bh * S_ * HD_;
  const int koff = grp << 10;           // group's key-range start

  bf16* kdb = smem + grp * 8192;        // group's K dbuf: 2 x 4096 elements
  bf16* pw  = smem + 16384 + w * 2048;  // wave's P: [64 q][32 keys], swizzled

  const int srow = lane >> 3;           // 0..7
  const int sg   = (lane & 7) ^ srow;

  // K staging: wave wl covers tile rows [16wl, 16wl+16), 2 DMA instrs
  const bf16* kptr = Kb + base + (size_t)(koff + 16 * wl + srow) * HD_ + 8 * sg;
  // V direct from L2: lane reads Vt[d = 16t2 + lr][key = koff + it*64 + ...]
  const bf16* vit  = Vt + base + (size_t)lr * S_ + koff + 8 * lq;

  // stage K tile 0 into buffer 0
  #pragma unroll
  for (int p = 0; p < 2; p++)
    async_load16(kptr + (size_t)8 * p * HD_, kdb + (16 * wl + 8 * p) * 64);

  // Q fragments from global (B-layout: n=lr -> q row, k=32kc+8lq+j)
  bf16x8 bq[4][2];
  #pragma unroll
  for (int g = 0; g < 4; g++) {
    const bf16* qrow = Q + base + (size_t)(q0 + 64 * wl + 16 * g + lr) * HD_;
    bq[g][0] = *reinterpret_cast<const bf16x8*>(qrow + lq * 8);
    bq[g][1] = *reinterpret_cast<const bf16x8*>(qrow + 32 + lq * 8);
  }

  const int sw0 = 8 * ((0 + lq) ^ (lr & 7));
  const int sw1 = 8 * ((4 + lq) ^ (lr & 7));
  const int plx = lr >> 1;              // 3-bit P-swizzle, orthogonal to lr&1

  float l_i[4] = {0.f, 0.f, 0.f, 0.f};
  floatx4 o_acc[4][4];
  #pragma unroll
  for (int g = 0; g < 4; g++)
    #pragma unroll
    for (int t = 0; t < 4; t++) o_acc[g][t] = floatx4{0.f, 0.f, 0.f, 0.f};

  __syncthreads();  // drain: tile 0 staged for both groups

  const bf16* kpf = kptr + (size_t)64 * HD_;  // prefetch base (tile 1)

  const int NIT = 16;                   // 1024 keys per group / 64
  for (int it = 0; it < NIT; it++) {
    bf16* ks = kdb + (it & 1) * 4096;

    // prefetch K tile it+1 into the other buffer (drained at loop-end sync)
    if (it + 1 < NIT) {
      bf16* ksn = kdb + ((it + 1) & 1) * 4096;
      #pragma unroll
      for (int p = 0; p < 2; p++)
        async_load16(kpf + (size_t)8 * p * HD_, ksn + (16 * wl + 8 * p) * 64);
      kpf += (size_t)64 * HD_;
    }

    // QK^T + exp + P-write for 16-key block t; P slot group = 4*(t&1)+lq
    auto qkt = [&](int t) {
      bf16x8 ak0 = *reinterpret_cast<const bf16x8*>(ks + (16 * t + lr) * 64 + sw0);
      bf16x8 ak1 = *reinterpret_cast<const bf16x8*>(ks + (16 * t + lr) * 64 + sw1);
      floatx4 sc[4];
      #pragma unroll
      for (int g = 0; g < 4; g++) {
        sc[g] = __builtin_amdgcn_mfma_f32_16x16x32_bf16(ak0, bq[g][0],
                    floatx4{0.f, 0.f, 0.f, 0.f}, 0, 0, 0);
        sc[g] = __builtin_amdgcn_mfma_f32_16x16x32_bf16(ak1, bq[g][1], sc[g], 0, 0, 0);
      }
      const int pcol = 4 * ((4 * (t & 1) + lq) ^ plx);
      #pragma unroll
      for (int g = 0; g < 4; g++) {
        bf16x4 pk;
        float lsum = 0.f;
        #pragma unroll
        for (int r = 0; r < 4; r++) {
          float p = __builtin_amdgcn_exp2f(sc[g][r]);
          lsum += p;
          pk[r] = (bf16)p;
        }
        l_i[g] += lsum;
        *reinterpret_cast<bf16x4*>(&pw[(16 * g + lr) * 32 + pcol]) = pk;
      }
    };

    // PV for one 32-key half; V fragments were loaded a phase early
    auto pv = [&](const bf16x8* av) {
      bf16x8 bp[4];
      #pragma unroll
      for (int g = 0; g < 4; g++) {
        union { bf16x4 h[2]; bf16x8 v; } f;
        f.h[0] = *reinterpret_cast<const bf16x4*>(
            &pw[(16 * g + lr) * 32 + 4 * ((2 * lq + 0) ^ plx)]);
        f.h[1] = *reinterpret_cast<const bf16x4*>(
            &pw[(16 * g + lr) * 32 + 4 * ((2 * lq + 1) ^ plx)]);
        bp[g] = f.v;
      }
      __builtin_amdgcn_s_setprio(1);
      #pragma unroll
      for (int t2 = 0; t2 < 4; t2++)
        #pragma unroll
        for (int g = 0; g < 4; g++)
          o_acc[g][t2] = __builtin_amdgcn_mfma_f32_16x16x32_bf16(av[t2], bp[g], o_acc[g][t2], 0, 0, 0);
      __builtin_amdgcn_s_setprio(0);
    };

    // A: V(kc=0) issued early; QK^T keys 0-31 -> P
    bf16x8 av0[4];
    #pragma unroll
    for (int t2 = 0; t2 < 4; t2++)
      av0[t2] = *reinterpret_cast<const bf16x8*>(vit + (size_t)16 * t2 * S_);
    qkt(0);
    qkt(1);
    __builtin_amdgcn_wave_barrier();  // pin ds_write -> ds_read (same wave)
    // B: PV kc=0
    pv(av0);
    __builtin_amdgcn_wave_barrier();  // pin B reads -> C overwrites
    // C: V(kc=1) issued early; QK^T keys 32-63 -> P (overwrite)
    bf16x8 av1[4];
    #pragma unroll
    for (int t2 = 0; t2 < 4; t2++)
      av1[t2] = *reinterpret_cast<const bf16x8*>(vit + (size_t)16 * t2 * S_ + 32);
    qkt(2);
    qkt(3);
    __builtin_amdgcn_wave_barrier();  // pin ds_write -> ds_read
    // D: PV kc=1
    pv(av1);

    vit += 64;
    __syncthreads();  // frees cur K buf; drains prefetch -> tile it+1 ready
  }

  // -------- cross-group reduction: grp1 partials -> LDS -> grp0 ----------
  // slot-major layout (slot*1024 + idx*4 floats): lanes contiguous 16B,
  // conflict-free. Two phases through the 32KB region + l_i alongside.
  float* red = (float*)smem;
  const int idx = tid & 255;            // grp0 thread <-> grp1 thread pairing
  if (grp == 1) {
    #pragma unroll
    for (int g = 0; g < 2; g++)
      #pragma unroll
      for (int t = 0; t < 4; t++)
        *reinterpret_cast<floatx4*>(red + (g * 4 + t) * 1024 + idx * 4) = o_acc[g][t];
    *reinterpret_cast<floatx4*>(red + 8192 + idx * 4) =
        floatx4{l_i[0], l_i[1], l_i[2], l_i[3]};
  }
  __syncthreads();
  if (grp == 0) {
    #pragma unroll
    for (int g = 0; g < 2; g++)
      #pragma unroll
      for (int t = 0; t < 4; t++)
        o_acc[g][t] += *reinterpret_cast<const floatx4*>(red + (g * 4 + t) * 1024 + idx * 4);
    floatx4 lv = *reinterpret_cast<const floatx4*>(red + 8192 + idx * 4);
    #pragma unroll
    for (int g = 0; g < 4; g++) l_i[g] += lv[g];
  }
  __syncthreads();
  if (grp == 1) {
    #pragma unroll
    for (int g = 2; g < 4; g++)
      #pragma unroll
      for (int t = 0; t < 4; t++)
        *reinterpret_cast<floatx4*>(red + ((g - 2) * 4 + t) * 1024 + idx * 4) = o_acc[g][t];
  }
  __syncthreads();
  if (grp == 0) {
    #pragma unroll
    for (int g = 2; g < 4; g++)
      #pragma unroll
      for (int t = 0; t < 4; t++)
        o_acc[g][t] += *reinterpret_cast<const floatx4*>(red + ((g - 2) * 4 + t) * 1024 + idx * 4);

    // finish denom: sum across the 4 lq groups sharing q=lr
    #pragma unroll
    for (int g = 0; g < 4; g++) {
      l_i[g] += __shfl_xor(l_i[g], 16, 64);
      l_i[g] += __shfl_xor(l_i[g], 32, 64);
    }

    // epilogue: out[b, s=q0+64wl+16g+lr, h*64 + 16t + 4lq + r]
    const int b = bh >> 4, h = bh & 15;
    #pragma unroll
    for (int g = 0; g < 4; g++) {
      const float inv = 1.0f / l_i[g];
      const int qrow = q0 + 64 * wl + 16 * g + lr;
      bf16* orow = out + ((size_t)b * S_ + qrow) * D_ + h * HD_;
      #pragma unroll
      for (int t = 0; t < 4; t++) {
        bf16x4 pk;
        #pragma unroll
        for (int r = 0; r < 4; r++) pk[r] = (bf16)(o_acc[g][t][r] * inv);
        *reinterpret_cast<bf16x4*>(&orow[16 * t + lq * 4]) = pk;
      }
    }
  }
}

// ---------------------------------------------------------------------------
extern "C" void kernel_launch(void* const* d_in, const int* in_sizes, int n_in,
                              void* d_out, int out_size, void* d_ws, size_t ws_size,
                              hipStream_t stream) {
  const float* X_Q   = (const float*)d_in[0];
  const float* X_KV  = (const float*)d_in[1];
  const float* q_w   = (const float*)d_in[2];
  const float* q_b   = (const float*)d_in[3];
  const float* kv_w  = (const float*)d_in[4];
  const float* kv_b  = (const float*)d_in[5];
  const float* out_w = (const float*)d_in[6];
  const float* out_b = (const float*)d_in[7];
  float* out = (float*)d_out;

  char* ws = (char*)d_ws;
  const size_t MB = 1024 * 1024;
  bf16* Xq   = (bf16*)(ws + 0);         // 16MB (reused as attn output later)
  bf16* Xkv  = (bf16*)(ws + 16 * MB);   // 16MB
  bf16* Qb   = (bf16*)(ws + 32 * MB);   // 16MB  [B,H,S,HD] (pre-scaled)
  bf16* Kb   = (bf16*)(ws + 48 * MB);   // 16MB  [B,H,S,HD]; Vt follows at +16MB
  bf16* qwT  = (bf16*)(ws + 80 * MB);   // 2MB   [N=1024][K=1024]
  bf16* kvwT = (bf16*)(ws + 82 * MB);   // 4MB   [N=2048][K=1024]
  bf16* owT  = (bf16*)(ws + 86 * MB);   // 2MB
  bf16* Vt   = Kb + (size_t)B_ * H_ * S_ * HD_;  // [B,H,HD,S]
  bf16* attn = Xq;                       // alias: X_Q bf16 dead after GEMM1

  // merged cast + weight transpose (one launch)
  prep_all<<<20480, 256, 0, stream>>>(X_Q, Xq, X_KV, Xkv,
                                      q_w, qwT, kv_w, kvwT, out_w, owT);
  // merged: Q = (Xq @ q_w + q_b)*QSCALE  and  KV = Xkv @ kv_w + kv_b
  gemm_qkv<<<1536, 256, 0, stream>>>(Xq, qwT, q_b, Qb, Xkv, kvwT, kv_b, Kb);
  // attention (8 waves: key-split groups x 256 q-rows; bh-major for XCD/L2)
  attn_kernel<<<dim3(64, 8), 512, 0, stream>>>(Qb, Kb, Vt, attn);
  // out = attn @ out_w + out_b  (fp32)
  gemm_out<<<dim3(8, 64), 256, 0, stream>>>(attn, owT, out_b, out, 8192, 1024, 1024);
}